// Round 5
// baseline (321.969 us; speedup 1.0000x reference)
//
#include <hip/hip_runtime.h>
#include <math.h>

#define NN 10000
#define NE 100000
#define NBATCH 64

typedef short bf16x8 __attribute__((ext_vector_type(8)));
typedef float f32x4 __attribute__((ext_vector_type(4)));

// lrelu(v) == max(v, 0.2v) for all v (bit-identical to the branch form; 2 VALU ops)
__device__ __forceinline__ float lrelu(float v){ return fmaxf(v, 0.2f*v); }

// fp32 -> bf16 round-to-nearest-even
__device__ __forceinline__ unsigned short f2bf(float x){
  unsigned int u = __float_as_uint(x);
  u += 0x7fffu + ((u >> 16) & 1u);
  return (unsigned short)(u >> 16);
}
__device__ __forceinline__ float bf2f(unsigned short u){
  return __uint_as_float(((unsigned int)u) << 16);
}

// ---------------- prep: zero + c1 precompute (+CTr) + 4 weight transposes --------------
__global__ __launch_bounds__(256) void prep_kernel(
    const float* __restrict__ vp_w, const float* __restrict__ vp_b,
    const float* __restrict__ type_emb,
    const float* __restrict__ c1_wl, const float* __restrict__ c1_bl,
    const float* __restrict__ c1_wr, const float* __restrict__ c1_br,
    float* __restrict__ Ul, float* __restrict__ CTl,
    float* __restrict__ Ur, float* __restrict__ CTr,
    const float* __restrict__ c2_wl, const float* __restrict__ c2_wr,
    const float* __restrict__ c3_wl, const float* __restrict__ c3_wr,
    unsigned short* __restrict__ W2lT, unsigned short* __restrict__ W2rT,
    unsigned short* __restrict__ W3lT, unsigned short* __restrict__ W3rT,
    float* __restrict__ zbase, int zero_words)
{
  __shared__ float t[64][65];
  int b = blockIdx.x;
  int tid = threadIdx.x;
  if (b < 144){
    const float* in; unsigned short* out; int K, N, idx;
    if (b < 64)      { in=c2_wl; out=W2lT; K=1024; N=256; idx=b; }
    else if (b <128) { in=c2_wr; out=W2rT; K=1024; N=256; idx=b-64; }
    else if (b <136) { in=c3_wl; out=W3lT; K=256;  N=128; idx=b-128; }
    else             { in=c3_wr; out=W3rT; K=256;  N=128; idx=b-136; }
    int K64 = K >> 6;
    int kx = idx % K64, nx = idx / K64;
    int k0 = kx*64, n0 = nx*64;
    int lr = tid >> 4;
    int lc = (tid & 15) * 4;
#pragma unroll
    for (int i=0;i<4;++i){
      int r = lr + i*16;
      float4 v = *(const float4*)(in + (size_t)(k0+r)*N + n0 + lc);
      t[r][lc+0]=v.x; t[r][lc+1]=v.y; t[r][lc+2]=v.z; t[r][lc+3]=v.w;
    }
    __syncthreads();
    int sr = tid >> 3;
    int sc = (tid & 7) * 8;
#pragma unroll
    for (int i=0;i<2;++i){
      int n = sr + i*32;
      unsigned short tmp[8];
#pragma unroll
      for (int j=0;j<8;++j) tmp[j] = f2bf(t[sc+j][n]);
      unsigned short* op = out + (size_t)(n0+n)*K + k0 + sc;
      *(ushort4*)op       = make_ushort4(tmp[0],tmp[1],tmp[2],tmp[3]);
      *(ushort4*)(op + 4) = make_ushort4(tmp[4],tmp[5],tmp[6],tmp[7]);
    }
  } else if (b < 148){
    int j = (b-144)*256 + tid;
    float ul=0.f, c0l=0.f, c1l=0.f, ur=0.f, c0r=0.f, c1r=0.f;
    for (int k=0; k<128; ++k){
      float a = c1_wl[k*1024 + j], bb = c1_wr[k*1024 + j];
      float vw = vp_w[k], vb = vp_b[k], t0 = type_emb[k], t1 = type_emb[128+k];
      ul += vw*a; ur += vw*bb;
      c0l += (vb+t0)*a; c1l += (vb+t1)*a;
      c0r += (vb+t0)*bb; c1r += (vb+t1)*bb;
    }
    float bl = c1_bl[j], br = c1_br[j];
    Ul[j]=ul; Ur[j]=ur;
    CTl[j]      = c0l + bl;
    CTl[1024+j] = c1l + bl;
    CTr[j]      = c0r + br;
    CTr[1024+j] = c1r + br;
  } else {
    for (int i = (b-148)*256 + tid; i < zero_words; i += 32*256)
      zbase[i] = 0.f;
  }
}

// ---------------- CSR build: 3 kernels (count -> scan -> fill) ----------------
__global__ void count_kernel(const int* __restrict__ dst, const float* __restrict__ ea,
                             int* __restrict__ deg, float* __restrict__ loop_sum){
  int e = blockIdx.x*256 + threadIdx.x;
  if (e < NE){
    int d = dst[e];
    atomicAdd(&deg[d], 1);
    atomicAdd(&loop_sum[d], ea[e]);
  }
}

// Single-block 3-phase scan (10 elems/thread), also emits loop_attr and the packed
// xt[n] = {x[n], (float)ntype[n]} node table used by all conv kernels.
__global__ __launch_bounds__(1024) void scan_kernel(const int* __restrict__ deg,
    const float* __restrict__ loop_sum, const float* __restrict__ x,
    const int* __restrict__ ntype,
    int* __restrict__ rowptr, float* __restrict__ loop_attr, float2* __restrict__ xt){
  __shared__ int wtot[16];
  int tid = threadIdx.x;
  int lane = tid & 63, wid = tid >> 6;
  int base = tid*10;
  int d[10]; int run = 0;
#pragma unroll
  for (int j=0;j<10;++j){
    int i = base + j;
    int v = (i < NN) ? deg[i] : 0;
    run += v; d[j] = run;                 // local inclusive
  }
  int T = run;
  int incl = T;
#pragma unroll
  for (int off=1; off<64; off<<=1){
    int s = __shfl_up(incl, off, 64);
    if (lane >= off) incl += s;
  }
  if (lane == 63) wtot[wid] = incl;
  __syncthreads();
  int wpre = 0;
  for (int w2=0; w2<wid; ++w2) wpre += wtot[w2];
  int ebase = wpre + incl - T;            // exclusive prefix of this thread's range
#pragma unroll
  for (int j=0;j<10;++j){
    int i = base + j;
    if (i < NN){
      int v = d[j] - ((j==0) ? 0 : d[j-1]);
      rowptr[i] = ebase + d[j] - v;
      loop_attr[i] = loop_sum[i] / fmaxf((float)v, 1.f);   // fill='mean'
      xt[i] = make_float2(x[i], (float)ntype[i]);
    }
  }
  if (tid == 1023) rowptr[NN] = wpre + incl;  // grand total (this thread's range is OOB)
}

__global__ void fill_kernel(const int* __restrict__ src, const int* __restrict__ dst,
                            const float* __restrict__ ea, const int* __restrict__ rowptr,
                            int* __restrict__ rowctr, int2* __restrict__ se){
  int e = blockIdx.x*256 + threadIdx.x;
  if (e < NE){
    int d = dst[e];
    int p = rowptr[d] + atomicAdd(&rowctr[d], 1);
    se[p] = make_int2(src[e], __float_as_int(ea[e]));
  }
}

// ---------------- conv1 FUSED: 1 wave/node, 16 ch/lane, plain-exp softmax --------------
// Lane = head*8 + sub; lane owns channels [h*128 + sub*16, +16). Per edge:
// z = xs*ul + ea*we + fmaf(tf, cnd, cn0), cn0/cnd folded per node.
// Scores are bounded (|s| <~ 3) -> plain exp accumulation, no max tracking: l, s1,
// st1 are independent FMA chains. s20 = 1 - st1/l. Depth-1 prefetch on se->xt chain.
__global__ __launch_bounds__(256) void conv1_fused(
    const int* __restrict__ rowptr, const int2* __restrict__ se,
    const float* __restrict__ loop_attr, const float2* __restrict__ xt,
    const float* __restrict__ Ul, const float* __restrict__ Ur,
    const float* __restrict__ CTl, const float* __restrict__ CTr,
    const float* __restrict__ we, const float* __restrict__ att,
    const float* __restrict__ bias, unsigned short* __restrict__ out)
{
  int n = blockIdx.x*4 + (threadIdx.x >> 6);
  if (n >= NN) return;
  int lane = threadIdx.x & 63;
  int h = lane >> 3, sub = lane & 7;
  int ch0 = h*128 + sub*16;
  float ul[16], wev[16], atv[16], cn0[16], cnd[16];
#pragma unroll
  for (int v=0; v<16; ++v){ ul[v]=Ul[ch0+v]; wev[v]=we[ch0+v]; atv[v]=att[ch0+v]; }
  int beg = rowptr[n], deg = rowptr[n+1]-beg;
  float2 xtn = xt[n];
  float xn = xtn.x, tfn = xtn.y;
  float la = loop_attr[n];
  const float* ctr = (tfn != 0.f) ? (CTr+1024) : CTr;
#pragma unroll
  for (int v=0; v<16; ++v){
    float c0 = CTl[ch0+v], c1 = CTl[1024+ch0+v];
    cn0[v] = fmaf(xn, Ur[ch0+v], ctr[ch0+v]) + c0;
    cnd[v] = c1 - c0;
  }
  const int2* sp = se + beg;
  float l = 0.f, s1 = 0.f, st1 = 0.f;
  // current edge state (idx deg == self-loop)
  int s; float ea;
  if (deg > 0){ int2 q = sp[0]; s = q.x; ea = __int_as_float(q.y); }
  else        { s = n; ea = la; }
  float2 xc = xt[s];
  for (int idx=0; idx<=deg; ++idx){
    // prefetch next edge
    int nx = idx+1;
    int2 qn;
    if (nx < deg) qn = sp[nx];
    else          qn = make_int2(n, __float_as_int(la));
    float2 xnx = xt[qn.x];
    // compute current edge
    float xs = xc.x, tf = xc.y;
    float acc = 0.f;
#pragma unroll
    for (int v=0; v<16; ++v){
      float t = fmaf(tf, cnd[v], cn0[v]);
      float z = fmaf(xs, ul[v], fmaf(ea, wev[v], t));
      acc = fmaf(atv[v], fmaxf(z, 0.2f*z), acc);
    }
    acc += __shfl_xor(acc, 1, 8);
    acc += __shfl_xor(acc, 2, 8);
    acc += __shfl_xor(acc, 4, 8);
    float pe = __expf(acc);
    l += pe;
    s1  = fmaf(pe, xs, s1);
    st1 = fmaf(pe, tf, st1);
    ea = __int_as_float(qn.y); xc = xnx;
  }
  float inv = 1.f/l;
  s1 *= inv;
  float s21 = st1 * inv;      // weight of type-1 sources
  float s20 = 1.f - s21;      // weight of type-0 sources
  bf16x8 w0v, w1v;
#pragma unroll
  for (int v=0; v<16; ++v){
    float c0 = CTl[ch0+v], c1 = CTl[1024+ch0+v];
    float o = lrelu(fmaf(s1, ul[v], fmaf(s20, c0, fmaf(s21, c1, bias[ch0+v]))));
    if (v < 8) w0v[v]   = (short)f2bf(o);
    else       w1v[v-8] = (short)f2bf(o);
  }
  unsigned short* op = out + (size_t)n*1024 + ch0;
  *(bf16x8*)op       = w0v;
  *(bf16x8*)(op + 8) = w1v;
}

// ---------------- generic fused GATv2 conv, QUAD-stream, plain-exp softmax ------------
// 4 independent accumulator streams -> 4 gathers in flight; no max tracking (scores
// bounded), so streams merge with plain adds. One node per wave, NPB waves per block.
// Packed se = {src, ea-bits}. Self-loop handled at index end.
template<int H, int NPB, int VPT, bool ONLY0, bool OUTBF, bool INBF>
__global__ __launch_bounds__(64*NPB) void conv_kernel(
    const int* __restrict__ rowptr, const int2* __restrict__ se,
    const float* __restrict__ loop_attr, const int* __restrict__ ntype,
    const void* __restrict__ Xv, int stride, int xr_off,
    const float* __restrict__ we, const float* __restrict__ att, const float* __restrict__ bias,
    void* __restrict__ out)
{
  const int HC = 64*VPT;
  const int TPH = 64/H;
  int n = blockIdx.x*NPB + (threadIdx.x >> 6);
  if (n >= NN) return;
  if (ONLY0 && ntype[n] != 0) return;
  int tid = threadIdx.x & 63;
  int ch0 = tid * VPT;
  const float* Xf = (const float*)Xv;
  const unsigned short* Xb = (const unsigned short*)Xv;
  float wev[VPT], atv[VPT], biv[VPT], xrv[VPT];
#pragma unroll
  for (int v=0; v<VPT; ++v){
    int ch = ch0+v;
    wev[v]=we[ch]; atv[v]=att[ch]; biv[v]=bias[ch];
  }
  if constexpr (INBF){
    ushort4 q = *(const ushort4*)(Xb + (size_t)n*stride + xr_off + ch0);
    xrv[0]=bf2f(q.x); xrv[1]=bf2f(q.y); xrv[2]=bf2f(q.z); xrv[3]=bf2f(q.w);
  } else {
#pragma unroll
    for (int v=0; v<VPT; ++v) xrv[v]=Xf[(size_t)n*stride + xr_off + ch0+v];
  }
  float ls[4], A[4][VPT];
#pragma unroll
  for (int k=0; k<4; ++k){
    ls[k] = 0.f;
#pragma unroll
    for (int v=0; v<VPT; ++v) A[k][v] = 0.f;
  }
  int beg=rowptr[n], end=rowptr[n+1];   // index end = self-loop
  float la = loop_attr[n];
  for (int j=beg; j<=end; j+=4){
    bool val[4]; int sx[4]; float ex[4];
#pragma unroll
    for (int k=0; k<4; ++k){
      int pos = j + k;
      val[k] = pos <= end;
      int2 q;
      if (pos < end) q = se[pos];
      else           q = make_int2(n, __float_as_int(la));   // self-loop / OOB (masked)
      sx[k] = q.x; ex[k] = __int_as_float(q.y);
    }
    float xv[4][VPT];
#pragma unroll
    for (int k=0; k<4; ++k){
      if constexpr (INBF){
        ushort4 q = *(const ushort4*)(Xb + (size_t)sx[k]*stride + ch0);
        xv[k][0]=bf2f(q.x); xv[k][1]=bf2f(q.y); xv[k][2]=bf2f(q.z); xv[k][3]=bf2f(q.w);
      } else if constexpr (VPT == 4){
        float4 q = *(const float4*)(Xf + (size_t)sx[k]*stride + ch0);
        xv[k][0]=q.x; xv[k][1]=q.y; xv[k][2]=q.z; xv[k][3]=q.w;
      } else {
        float2 q = *(const float2*)(Xf + (size_t)sx[k]*stride + ch0);
        xv[k][0]=q.x; xv[k][1]=q.y;
      }
    }
    float p[4];
#pragma unroll
    for (int k=0; k<4; ++k){
      float acc = 0.f;
#pragma unroll
      for (int v=0; v<VPT; ++v)
        acc += atv[v]*lrelu(xv[k][v]+xrv[v]+ex[k]*wev[v]);
      p[k] = acc;
    }
#pragma unroll
    for (int mm=1; mm<TPH; mm<<=1){
#pragma unroll
      for (int k=0; k<4; ++k) p[k] += __shfl_xor(p[k], mm, 64);
    }
#pragma unroll
    for (int k=0; k<4; ++k){
      float pe = val[k] ? __expf(p[k]) : 0.f;
      ls[k] += pe;
#pragma unroll
      for (int v=0; v<VPT; ++v) A[k][v] = fmaf(pe, xv[k][v], A[k][v]);
    }
  }
  float lt = (ls[0]+ls[1]) + (ls[2]+ls[3]);
  float inv = 1.f/lt;
  size_t baseo=(size_t)n*HC+ch0;
  if constexpr (OUTBF){
    unsigned short* ob = (unsigned short*)out;
    ushort4 o;
    o.x = f2bf(lrelu(((A[0][0]+A[1][0])+(A[2][0]+A[3][0]))*inv+biv[0]));
    o.y = f2bf(lrelu(((A[0][1]+A[1][1])+(A[2][1]+A[3][1]))*inv+biv[1]));
    o.z = f2bf(lrelu(((A[0][2]+A[1][2])+(A[2][2]+A[3][2]))*inv+biv[2]));
    o.w = f2bf(lrelu(((A[0][3]+A[1][3])+(A[2][3]+A[3][3]))*inv+biv[3]));
    *(ushort4*)(ob + baseo) = o;
  } else {
    float* of = (float*)out;
#pragma unroll
    for (int v=0; v<VPT; ++v)
      of[baseo+v] = lrelu(((A[0][v]+A[1][v])+(A[2][v]+A[3][v]))*inv+biv[v]);
  }
}

// ---------------- bf16 MFMA dual GEMM, LDS-staged via global_load_lds (m97 style) -----
template<bool OUTBF>
__global__ __launch_bounds__(256) void gemm_dual_lds(
    const short* __restrict__ Abf,
    const short* __restrict__ WlT, const short* __restrict__ WrT,
    const float* __restrict__ bl, const float* __restrict__ br,
    void* __restrict__ Out, int M, int K, int NcH, int cgrid, int rgrid)
{
  __shared__ short lds[12288];    // A: [0,8192) shorts (128 rows x 64), B: [8192,12288)
  int id = blockIdx.x;
  int xcd = id & 7, slot = id >> 3;
  int nb = slot % cgrid;
  int rowgroup = (slot / cgrid) * 8 + xcd;
  if (rowgroup >= rgrid) return;
  int row0 = rowgroup * 128;
  int NC2 = 2*NcH;
  int halfx = NcH >> 6;
  int isR = nb >= halfx;
  const short* WT = isR ? WrT : WlT;
  const float* bias = isR ? br : bl;
  int col0 = (nb - (isR ? halfx : 0)) * 64;
  int gcol0 = nb * 64;
  int tid = threadIdx.x;
  int lane = tid & 63, wave = tid >> 6;
  int wm = wave >> 1, wn = wave & 1;
  int quad = lane >> 4, l16 = lane & 15;

  const short* asrc[4];
#pragma unroll
  for (int i=0;i<4;++i){
    int c = wave*256 + i*64 + lane;
    int m = c >> 3, j = c & 7;
    int gr = row0 + m; gr = gr < M ? gr : M-1;   // clamp; never stored
    asrc[i] = Abf + (size_t)gr*K + ((j ^ (m & 7)) << 3);
  }
  const short* bsrc[2];
#pragma unroll
  for (int i=0;i<2;++i){
    int c = wave*128 + i*64 + lane;
    int nloc = c >> 3, j = c & 7;
    bsrc[i] = WT + (size_t)(col0 + nloc)*K + ((j ^ (nloc & 7)) << 3);
  }

  float biasv[2] = { bias[col0 + wn*32 + l16], bias[col0 + wn*32 + 16 + l16] };
  f32x4 acc[4][2];
#pragma unroll
  for (int f=0; f<4; ++f)
#pragma unroll
    for (int g=0; g<2; ++g) acc[f][g] = (f32x4){0.f,0.f,0.f,0.f};

  int niter = K >> 6;
  for (int it=0; it<niter; ++it){
    int k0 = it << 6;
#pragma unroll
    for (int i=0;i<4;++i)
      __builtin_amdgcn_global_load_lds(asrc[i] + k0, &lds[(wave*256 + i*64)*8], 16, 0, 0);
#pragma unroll
    for (int i=0;i<2;++i)
      __builtin_amdgcn_global_load_lds(bsrc[i] + k0, &lds[8192 + (wave*128 + i*64)*8], 16, 0, 0);
    __syncthreads();
#pragma unroll
    for (int s=0; s<2; ++s){
      int t = s*4 + quad;
      bf16x8 af[4], bfv[2];
#pragma unroll
      for (int f=0; f<4; ++f){
        int m = wm*64 + f*16 + l16;
        af[f] = *(const bf16x8*)&lds[m*64 + ((t ^ (m & 7)) << 3)];
      }
#pragma unroll
      for (int g=0; g<2; ++g){
        int nloc = wn*32 + g*16 + l16;
        bfv[g] = *(const bf16x8*)&lds[8192 + nloc*64 + ((t ^ (nloc & 7)) << 3)];
      }
#pragma unroll
      for (int f=0; f<4; ++f)
#pragma unroll
        for (int g=0; g<2; ++g)
          acc[f][g] = __builtin_amdgcn_mfma_f32_16x16x32_bf16(af[f], bfv[g], acc[f][g], 0,0,0);
    }
    __syncthreads();
  }

#pragma unroll
  for (int f=0; f<4; ++f){
    int rbase = row0 + wm*64 + f*16 + quad*4;
#pragma unroll
    for (int r=0; r<4; ++r){
      int rr = rbase + r;
      if (rr < M){
#pragma unroll
        for (int g=0; g<2; ++g){
          int cc = gcol0 + wn*32 + g*16 + l16;
          float val = acc[f][g][r] + biasv[g];
          if constexpr (OUTBF) ((unsigned short*)Out)[(size_t)rr*NC2 + cc] = f2bf(val);
          else                 ((float*)Out)[(size_t)rr*NC2 + cc] = val;
        }
      }
    }
  }
}

// ---------------- fused pool (sorted batch, binary search) + MLP head ----------------
__device__ __forceinline__ int lbound(const int* __restrict__ a, int n, int key){
  int lo = 0, hi = n;
  while (lo < hi){ int mid = (lo+hi) >> 1; if (a[mid] < key) lo = mid+1; else hi = mid; }
  return lo;
}

__global__ __launch_bounds__(128) void head_kernel(
    const float* __restrict__ h3, const int* __restrict__ ntype, const int* __restrict__ batch,
    const float* __restrict__ m1w, const float* __restrict__ m1b,
    const float* __restrict__ g1, const float* __restrict__ b1,
    const float* __restrict__ m2w, const float* __restrict__ m2b,
    const float* __restrict__ g2, const float* __restrict__ b2,
    const float* __restrict__ m3w, const float* __restrict__ m3b,
    float* __restrict__ out)
{
  __shared__ float p[128];
  __shared__ float hb[128];
  __shared__ float red[128];
  int b = blockIdx.x, j = threadIdx.x;
  int lo = lbound(batch, NN, b);
  int hi = lbound(batch, NN, b+1);
  float s = 0.f, cnt = 0.f;
  int n = lo;
  for (; n + 3 < hi; n += 4){
    float w0 = (ntype[n]   == 0) ? 1.f : 0.f;
    float w1 = (ntype[n+1] == 0) ? 1.f : 0.f;
    float w2 = (ntype[n+2] == 0) ? 1.f : 0.f;
    float w3 = (ntype[n+3] == 0) ? 1.f : 0.f;
    s += w0*h3[(size_t)n*128 + j]     + w1*h3[(size_t)(n+1)*128 + j]
       + w2*h3[(size_t)(n+2)*128 + j] + w3*h3[(size_t)(n+3)*128 + j];
    cnt += w0 + w1 + w2 + w3;
  }
  for (; n < hi; ++n){
    float w = (ntype[n] == 0) ? 1.f : 0.f;
    s += w*h3[(size_t)n*128 + j];
    cnt += w;
  }
  p[j] = s / fmaxf(cnt, 1.f);
  __syncthreads();
  float a = m1b[j];
  for (int k=0; k<128; ++k) a += p[k]*m1w[k*128 + j];
  red[j] = a; __syncthreads();
  for (int off=64; off>0; off>>=1){ if (j<off) red[j] += red[j+off]; __syncthreads(); }
  float mu = red[0] * (1.f/128.f);
  __syncthreads();
  float d = a - mu;
  red[j] = d*d; __syncthreads();
  for (int off=64; off>0; off>>=1){ if (j<off) red[j] += red[j+off]; __syncthreads(); }
  float var = red[0] * (1.f/128.f);
  __syncthreads();
  hb[j] = lrelu(d * rsqrtf(var + 1e-5f) * g1[j] + b1[j]);
  __syncthreads();
  float a2 = 0.f;
  if (j < 64){
    a2 = m2b[j];
    for (int k=0; k<128; ++k) a2 += hb[k]*m2w[k*64 + j];
  }
  red[j] = (j<64) ? a2 : 0.f; __syncthreads();
  for (int off=64; off>0; off>>=1){ if (j<off) red[j] += red[j+off]; __syncthreads(); }
  float mu2 = red[0] * (1.f/64.f);
  __syncthreads();
  float d2 = a2 - mu2;
  red[j] = (j<64) ? d2*d2 : 0.f; __syncthreads();
  for (int off=64; off>0; off>>=1){ if (j<off) red[j] += red[j+off]; __syncthreads(); }
  float var2 = red[0] * (1.f/64.f);
  __syncthreads();
  if (j < 64) hb[j] = lrelu(d2 * rsqrtf(var2 + 1e-5f) * g2[j] + b2[j]);
  __syncthreads();
  if (j == 0){
    float o = m3b[0];
    for (int k=0; k<64; ++k) o += hb[k]*m3w[k];
    out[b] = o;
  }
}

extern "C" void kernel_launch(void* const* d_in, const int* in_sizes, int n_in,
                              void* d_out, int out_size, void* d_ws, size_t ws_size,
                              hipStream_t stream)
{
  const float* x        = (const float*)d_in[0];
  const int*   ntype    = (const int*)d_in[1];
  const int*   ei       = (const int*)d_in[2];
  const float* eattr    = (const float*)d_in[3];
  const int*   batch    = (const int*)d_in[4];
  const float* vp_w     = (const float*)d_in[5];
  const float* vp_b     = (const float*)d_in[6];
  const float* type_emb = (const float*)d_in[7];
  const float* c1_wl = (const float*)d_in[8];  const float* c1_bl = (const float*)d_in[9];
  const float* c1_wr = (const float*)d_in[10]; const float* c1_br = (const float*)d_in[11];
  const float* c1_we = (const float*)d_in[12]; const float* c1_att= (const float*)d_in[13];
  const float* c1_bias=(const float*)d_in[14];
  const float* c2_wl = (const float*)d_in[15]; const float* c2_bl = (const float*)d_in[16];
  const float* c2_wr = (const float*)d_in[17]; const float* c2_br = (const float*)d_in[18];
  const float* c2_we = (const float*)d_in[19]; const float* c2_att= (const float*)d_in[20];
  const float* c2_bias=(const float*)d_in[21];
  const float* c3_wl = (const float*)d_in[22]; const float* c3_bl = (const float*)d_in[23];
  const float* c3_wr = (const float*)d_in[24]; const float* c3_br = (const float*)d_in[25];
  const float* c3_we = (const float*)d_in[26]; const float* c3_att= (const float*)d_in[27];
  const float* c3_bias=(const float*)d_in[28];
  const float* m1_w = (const float*)d_in[29]; const float* m1_b = (const float*)d_in[30];
  const float* ln1_g= (const float*)d_in[31]; const float* ln1_b= (const float*)d_in[32];
  const float* m2_w = (const float*)d_in[33]; const float* m2_b = (const float*)d_in[34];
  const float* ln2_g= (const float*)d_in[35]; const float* ln2_b= (const float*)d_in[36];
  const float* m3_w = (const float*)d_in[37]; const float* m3_b = (const float*)d_in[38];
  const int* esrc = ei;
  const int* edst = ei + NE;
  float* outp = (float*)d_out;
  (void)in_sizes; (void)n_in; (void)out_size; (void)ws_size;

  // ---- workspace arena ----
  char* w = (char*)d_ws;
  auto alloc = [&](size_t bytes) -> void* {
    void* p = (void*)w;
    w += (bytes + 255) & ~(size_t)255;
    return p;
  };
  unsigned short* h1bf = (unsigned short*)alloc((size_t)NN*1024*2);  // conv1 out, bf16
  unsigned short* X2   = (unsigned short*)alloc((size_t)NN*512*2);   // [xl2 | xr2] bf16
  unsigned short* h2bf = (unsigned short*)alloc((size_t)NN*256*2);   // conv2 out, bf16
  float* X3   = (float*)alloc((size_t)NN*256*4);    // [xl3 | xr3] fp32
  float* h3   = (float*)alloc((size_t)NN*128*4);    // conv3 out (type0 rows only)
  unsigned short* W2lT = (unsigned short*)alloc((size_t)256*1024*2);
  unsigned short* W2rT = (unsigned short*)alloc((size_t)256*1024*2);
  unsigned short* W3lT = (unsigned short*)alloc((size_t)128*256*2);
  unsigned short* W3rT = (unsigned short*)alloc((size_t)128*256*2);
  float* Ul   = (float*)alloc(1024*4);
  float* CTl  = (float*)alloc(2048*4);
  float* Ur   = (float*)alloc(1024*4);
  float* CTr  = (float*)alloc(2048*4);
  const int zero_words = 3*NN;                       // deg, rowctr, loop_sum
  float* zbase = (float*)alloc((size_t)zero_words*4);
  int*   deg      = (int*)zbase;
  int*   rowctr   = (int*)(zbase + NN);
  float* loop_sum = zbase + 2*NN;
  float* loop_attr= (float*)alloc((size_t)NN*4);
  float2* xt      = (float2*)alloc((size_t)NN*8);    // {x, (float)ntype}
  int*   rowptr   = (int*)alloc((size_t)(NN+1)*4);
  int2*  se       = (int2*)alloc((size_t)NE*8);      // {src, ea bits}

  // ---- pipeline (10 dispatches) ----
  prep_kernel<<<180, 256, 0, stream>>>(vp_w, vp_b, type_emb,
      c1_wl, c1_bl, c1_wr, c1_br, Ul, CTl, Ur, CTr,
      c2_wl, c2_wr, c3_wl, c3_wr, W2lT, W2rT, W3lT, W3rT,
      zbase, zero_words);
  count_kernel<<<(NE+255)/256, 256, 0, stream>>>(edst, eattr, deg, loop_sum);
  scan_kernel<<<1, 1024, 0, stream>>>(deg, loop_sum, x, ntype, rowptr, loop_attr, xt);
  fill_kernel<<<(NE+255)/256, 256, 0, stream>>>(esrc, edst, eattr, rowptr, rowctr, se);
  conv1_fused<<<NN/4, 256, 0, stream>>>(rowptr, se, loop_attr, xt,
      Ul, Ur, CTl, CTr, c1_we, c1_att, c1_bias, h1bf);
  // c2: X2[10000,512] bf16, K=1024, NcH=256: cgrid=8, rgrid=79 -> 640 blocks
  gemm_dual_lds<true><<<640, 256, 0, stream>>>(
      (const short*)h1bf, (const short*)W2lT, (const short*)W2rT, c2_bl, c2_br,
      (void*)X2, NN, 1024, 256, 8, 79);
  conv_kernel<2,4,4,false,true,true><<<NN/4, 256, 0, stream>>>(rowptr, se, loop_attr, ntype,
      (const void*)X2, 512, 256, c2_we, c2_att, c2_bias, h2bf);
  // c3: X3[10000,256] fp32, K=256, NcH=128: cgrid=4, rgrid=79 -> 320 blocks
  gemm_dual_lds<false><<<320, 256, 0, stream>>>(
      (const short*)h2bf, (const short*)W3lT, (const short*)W3rT, c3_bl, c3_br,
      (void*)X3, NN, 256, 128, 4, 79);
  conv_kernel<1,4,2,true,false,false><<<NN/4, 256, 0, stream>>>(rowptr, se, loop_attr, ntype,
      (const void*)X3, 256, 128, c3_we, c3_att, c3_bias, h3);
  head_kernel<<<NBATCH, 128, 0, stream>>>(h3, ntype, batch, m1_w, m1_b, ln1_g, ln1_b,
                                          m2_w, m2_b, ln2_g, ln2_b, m3_w, m3_b, outp);
}

// Round 6
// 314.479 us; speedup vs baseline: 1.0238x; 1.0238x over previous
//
#include <hip/hip_runtime.h>
#include <math.h>

#define NN 10000
#define NE 100000
#define NBATCH 64

typedef short bf16x8 __attribute__((ext_vector_type(8)));
typedef float f32x4 __attribute__((ext_vector_type(4)));

// lrelu(v) == max(v, 0.2v) for all v (bit-identical to the branch form; 2 VALU ops)
__device__ __forceinline__ float lrelu(float v){ return fmaxf(v, 0.2f*v); }

// fp32 -> bf16 round-to-nearest-even
__device__ __forceinline__ unsigned short f2bf(float x){
  unsigned int u = __float_as_uint(x);
  u += 0x7fffu + ((u >> 16) & 1u);
  return (unsigned short)(u >> 16);
}
__device__ __forceinline__ float bf2f(unsigned short u){
  return __uint_as_float(((unsigned int)u) << 16);
}

// ---------------- prep: zero + c1 precompute (+CTr) + 4 weight transposes --------------
__global__ __launch_bounds__(256) void prep_kernel(
    const float* __restrict__ vp_w, const float* __restrict__ vp_b,
    const float* __restrict__ type_emb,
    const float* __restrict__ c1_wl, const float* __restrict__ c1_bl,
    const float* __restrict__ c1_wr, const float* __restrict__ c1_br,
    float* __restrict__ Ul, float* __restrict__ CTl,
    float* __restrict__ Ur, float* __restrict__ CTr,
    const float* __restrict__ c2_wl, const float* __restrict__ c2_wr,
    const float* __restrict__ c3_wl, const float* __restrict__ c3_wr,
    unsigned short* __restrict__ W2lT, unsigned short* __restrict__ W2rT,
    unsigned short* __restrict__ W3lT, unsigned short* __restrict__ W3rT,
    float* __restrict__ zbase, int zero_words)
{
  __shared__ float t[64][65];
  int b = blockIdx.x;
  int tid = threadIdx.x;
  if (b < 144){
    const float* in; unsigned short* out; int K, N, idx;
    if (b < 64)      { in=c2_wl; out=W2lT; K=1024; N=256; idx=b; }
    else if (b <128) { in=c2_wr; out=W2rT; K=1024; N=256; idx=b-64; }
    else if (b <136) { in=c3_wl; out=W3lT; K=256;  N=128; idx=b-128; }
    else             { in=c3_wr; out=W3rT; K=256;  N=128; idx=b-136; }
    int K64 = K >> 6;
    int kx = idx % K64, nx = idx / K64;
    int k0 = kx*64, n0 = nx*64;
    int lr = tid >> 4;
    int lc = (tid & 15) * 4;
#pragma unroll
    for (int i=0;i<4;++i){
      int r = lr + i*16;
      float4 v = *(const float4*)(in + (size_t)(k0+r)*N + n0 + lc);
      t[r][lc+0]=v.x; t[r][lc+1]=v.y; t[r][lc+2]=v.z; t[r][lc+3]=v.w;
    }
    __syncthreads();
    int sr = tid >> 3;
    int sc = (tid & 7) * 8;
#pragma unroll
    for (int i=0;i<2;++i){
      int n = sr + i*32;
      unsigned short tmp[8];
#pragma unroll
      for (int j=0;j<8;++j) tmp[j] = f2bf(t[sc+j][n]);
      unsigned short* op = out + (size_t)(n0+n)*K + k0 + sc;
      *(ushort4*)op       = make_ushort4(tmp[0],tmp[1],tmp[2],tmp[3]);
      *(ushort4*)(op + 4) = make_ushort4(tmp[4],tmp[5],tmp[6],tmp[7]);
    }
  } else if (b < 148){
    int j = (b-144)*256 + tid;
    float ul=0.f, c0l=0.f, c1l=0.f, ur=0.f, c0r=0.f, c1r=0.f;
    for (int k=0; k<128; ++k){
      float a = c1_wl[k*1024 + j], bb = c1_wr[k*1024 + j];
      float vw = vp_w[k], vb = vp_b[k], t0 = type_emb[k], t1 = type_emb[128+k];
      ul += vw*a; ur += vw*bb;
      c0l += (vb+t0)*a; c1l += (vb+t1)*a;
      c0r += (vb+t0)*bb; c1r += (vb+t1)*bb;
    }
    float bl = c1_bl[j], br = c1_br[j];
    Ul[j]=ul; Ur[j]=ur;
    CTl[j]      = c0l + bl;
    CTl[1024+j] = c1l + bl;
    CTr[j]      = c0r + br;
    CTr[1024+j] = c1r + br;
  } else {
    for (int i = (b-148)*256 + tid; i < zero_words; i += 32*256)
      zbase[i] = 0.f;
  }
}

// ---------------- CSR build: 3 kernels (count -> scan -> fill) ----------------
__global__ void count_kernel(const int* __restrict__ dst, const float* __restrict__ ea,
                             int* __restrict__ deg, float* __restrict__ loop_sum){
  int e = blockIdx.x*256 + threadIdx.x;
  if (e < NE){
    int d = dst[e];
    atomicAdd(&deg[d], 1);
    atomicAdd(&loop_sum[d], ea[e]);
  }
}

// Single-block 3-phase scan (10 elems/thread), also emits loop_attr and the packed
// xt[n] = {x[n], (float)ntype[n]} node table used by all conv kernels.
__global__ __launch_bounds__(1024) void scan_kernel(const int* __restrict__ deg,
    const float* __restrict__ loop_sum, const float* __restrict__ x,
    const int* __restrict__ ntype,
    int* __restrict__ rowptr, float* __restrict__ loop_attr, float2* __restrict__ xt){
  __shared__ int wtot[16];
  int tid = threadIdx.x;
  int lane = tid & 63, wid = tid >> 6;
  int base = tid*10;
  int d[10]; int run = 0;
#pragma unroll
  for (int j=0;j<10;++j){
    int i = base + j;
    int v = (i < NN) ? deg[i] : 0;
    run += v; d[j] = run;                 // local inclusive
  }
  int T = run;
  int incl = T;
#pragma unroll
  for (int off=1; off<64; off<<=1){
    int s = __shfl_up(incl, off, 64);
    if (lane >= off) incl += s;
  }
  if (lane == 63) wtot[wid] = incl;
  __syncthreads();
  int wpre = 0;
  for (int w2=0; w2<wid; ++w2) wpre += wtot[w2];
  int ebase = wpre + incl - T;            // exclusive prefix of this thread's range
#pragma unroll
  for (int j=0;j<10;++j){
    int i = base + j;
    if (i < NN){
      int v = d[j] - ((j==0) ? 0 : d[j-1]);
      rowptr[i] = ebase + d[j] - v;
      loop_attr[i] = loop_sum[i] / fmaxf((float)v, 1.f);   // fill='mean'
      xt[i] = make_float2(x[i], (float)ntype[i]);
    }
  }
  if (tid == 1023) rowptr[NN] = wpre + incl;  // grand total (this thread's range is OOB)
}

__global__ void fill_kernel(const int* __restrict__ src, const int* __restrict__ dst,
                            const float* __restrict__ ea, const int* __restrict__ rowptr,
                            int* __restrict__ rowctr, int2* __restrict__ se){
  int e = blockIdx.x*256 + threadIdx.x;
  if (e < NE){
    int d = dst[e];
    int p = rowptr[d] + atomicAdd(&rowctr[d], 1);
    se[p] = make_int2(src[e], __float_as_int(ea[e]));
  }
}

// ---------------- conv1 FUSED: 2 nodes/block, 128 thr/node, plain-exp softmax ---------
// Lane te owns 8 ch (head = te>>4, 16 lanes/head). Per edge:
// z = xs*ul + ea*we + fmaf(tf, cnd, cn0); acc -> 4-step width-16 butterfly; plain exp
// (scores bounded |s|<~3 -> no max tracking; l,s1,st1 independent FMA chains).
// Depth-2 software pipeline on the se->xt two-load chain: at iter top, issue se(i+2)
// and xt[se(i+1)] (se(i+1) returned during previous iteration's compute).
__global__ __launch_bounds__(256) void conv1_fused(
    const int* __restrict__ rowptr, const int2* __restrict__ se,
    const float* __restrict__ loop_attr, const float2* __restrict__ xt,
    const float* __restrict__ Ul, const float* __restrict__ Ur,
    const float* __restrict__ CTl, const float* __restrict__ CTr,
    const float* __restrict__ we, const float* __restrict__ att,
    const float* __restrict__ bias, unsigned short* __restrict__ out)
{
  int n = blockIdx.x*2 + (threadIdx.x >> 7);
  if (n >= NN) return;
  int te = threadIdx.x & 127;
  int ch0 = te * 8;                      // head = te>>4
  float ul[8], wev[8], atv[8], cn0[8], cnd[8];
#pragma unroll
  for (int v=0; v<8; ++v){ ul[v]=Ul[ch0+v]; wev[v]=we[ch0+v]; atv[v]=att[ch0+v]; }
  int beg = rowptr[n], deg = rowptr[n+1]-beg;
  float2 xtn = xt[n];
  float la = loop_attr[n];
  const float* ctr = (xtn.y != 0.f) ? (CTr+1024) : CTr;
#pragma unroll
  for (int v=0; v<8; ++v){
    float c0 = CTl[ch0+v], c1 = CTl[1024+ch0+v];
    cn0[v] = fmaf(xtn.x, Ur[ch0+v], ctr[ch0+v]) + c0;
    cnd[v] = c1 - c0;
  }
  const int2* sp = se + beg;
  const int2 self = make_int2(n, __float_as_int(la));
  // pipeline prologue: edge(i) = (i<deg) ? sp[i] : self  (self-loop at idx==deg)
  int2 qc = (deg > 0) ? sp[0] : self;    // edge 0
  float2 xc = xt[qc.x];
  int2 qn = (1 < deg) ? sp[1] : self;    // edge 1
  float l = 0.f, s1 = 0.f, st1 = 0.f;
  for (int idx=0; idx<=deg; ++idx){
    // issue future loads first (independent of current compute)
    int2 qnn = (idx+2 < deg) ? sp[idx+2] : self;   // edge idx+2
    float2 xn = xt[qn.x];                          // edge idx+1's xt (qn returned)
    // compute current edge
    float xs = xc.x, tf = xc.y, ea = __int_as_float(qc.y);
    float acc = 0.f;
#pragma unroll
    for (int v=0; v<8; ++v){
      float t = fmaf(tf, cnd[v], cn0[v]);
      float z = fmaf(xs, ul[v], fmaf(ea, wev[v], t));
      acc = fmaf(atv[v], fmaxf(z, 0.2f*z), acc);
    }
    acc += __shfl_xor(acc, 1, 16);
    acc += __shfl_xor(acc, 2, 16);
    acc += __shfl_xor(acc, 4, 16);
    acc += __shfl_xor(acc, 8, 16);
    float pe = __expf(acc);
    l += pe;
    s1  = fmaf(pe, xs, s1);
    st1 = fmaf(pe, tf, st1);
    // rotate pipeline
    qc = qn; xc = xn; qn = qnn;
  }
  float inv = 1.f/l;
  s1 *= inv;
  float s21 = st1 * inv;      // weight of type-1 sources
  float s20 = 1.f - s21;      // weight of type-0 sources
  bf16x8 ov;
#pragma unroll
  for (int v=0; v<8; ++v){
    float c0 = CTl[ch0+v], c1 = CTl[1024+ch0+v];
    float o = lrelu(fmaf(s1, ul[v], fmaf(s20, c0, fmaf(s21, c1, bias[ch0+v]))));
    ov[v] = (short)f2bf(o);
  }
  *(bf16x8*)(out + (size_t)n*1024 + ch0) = ov;
}

// ---------------- generic fused GATv2 conv, QUAD-stream, plain-exp softmax ------------
// 4 independent accumulator streams -> 4 gathers in flight; no max tracking (scores
// bounded), so streams merge with plain adds. One node per wave, NPB waves per block.
// Packed se = {src, ea-bits}. Self-loop handled at index end.
template<int H, int NPB, int VPT, bool ONLY0, bool OUTBF, bool INBF>
__global__ __launch_bounds__(64*NPB) void conv_kernel(
    const int* __restrict__ rowptr, const int2* __restrict__ se,
    const float* __restrict__ loop_attr, const int* __restrict__ ntype,
    const void* __restrict__ Xv, int stride, int xr_off,
    const float* __restrict__ we, const float* __restrict__ att, const float* __restrict__ bias,
    void* __restrict__ out)
{
  const int HC = 64*VPT;
  const int TPH = 64/H;
  int n = blockIdx.x*NPB + (threadIdx.x >> 6);
  if (n >= NN) return;
  if (ONLY0 && ntype[n] != 0) return;
  int tid = threadIdx.x & 63;
  int ch0 = tid * VPT;
  const float* Xf = (const float*)Xv;
  const unsigned short* Xb = (const unsigned short*)Xv;
  float wev[VPT], atv[VPT], biv[VPT], xrv[VPT];
#pragma unroll
  for (int v=0; v<VPT; ++v){
    int ch = ch0+v;
    wev[v]=we[ch]; atv[v]=att[ch]; biv[v]=bias[ch];
  }
  if constexpr (INBF){
    ushort4 q = *(const ushort4*)(Xb + (size_t)n*stride + xr_off + ch0);
    xrv[0]=bf2f(q.x); xrv[1]=bf2f(q.y); xrv[2]=bf2f(q.z); xrv[3]=bf2f(q.w);
  } else {
#pragma unroll
    for (int v=0; v<VPT; ++v) xrv[v]=Xf[(size_t)n*stride + xr_off + ch0+v];
  }
  float ls[4], A[4][VPT];
#pragma unroll
  for (int k=0; k<4; ++k){
    ls[k] = 0.f;
#pragma unroll
    for (int v=0; v<VPT; ++v) A[k][v] = 0.f;
  }
  int beg=rowptr[n], end=rowptr[n+1];   // index end = self-loop
  float la = loop_attr[n];
  for (int j=beg; j<=end; j+=4){
    bool val[4]; int sx[4]; float ex[4];
#pragma unroll
    for (int k=0; k<4; ++k){
      int pos = j + k;
      val[k] = pos <= end;
      int2 q;
      if (pos < end) q = se[pos];
      else           q = make_int2(n, __float_as_int(la));   // self-loop / OOB (masked)
      sx[k] = q.x; ex[k] = __int_as_float(q.y);
    }
    float xv[4][VPT];
#pragma unroll
    for (int k=0; k<4; ++k){
      if constexpr (INBF){
        ushort4 q = *(const ushort4*)(Xb + (size_t)sx[k]*stride + ch0);
        xv[k][0]=bf2f(q.x); xv[k][1]=bf2f(q.y); xv[k][2]=bf2f(q.z); xv[k][3]=bf2f(q.w);
      } else if constexpr (VPT == 4){
        float4 q = *(const float4*)(Xf + (size_t)sx[k]*stride + ch0);
        xv[k][0]=q.x; xv[k][1]=q.y; xv[k][2]=q.z; xv[k][3]=q.w;
      } else {
        float2 q = *(const float2*)(Xf + (size_t)sx[k]*stride + ch0);
        xv[k][0]=q.x; xv[k][1]=q.y;
      }
    }
    float p[4];
#pragma unroll
    for (int k=0; k<4; ++k){
      float acc = 0.f;
#pragma unroll
      for (int v=0; v<VPT; ++v)
        acc += atv[v]*lrelu(xv[k][v]+xrv[v]+ex[k]*wev[v]);
      p[k] = acc;
    }
#pragma unroll
    for (int mm=1; mm<TPH; mm<<=1){
#pragma unroll
      for (int k=0; k<4; ++k) p[k] += __shfl_xor(p[k], mm, 64);
    }
#pragma unroll
    for (int k=0; k<4; ++k){
      float pe = val[k] ? __expf(p[k]) : 0.f;
      ls[k] += pe;
#pragma unroll
      for (int v=0; v<VPT; ++v) A[k][v] = fmaf(pe, xv[k][v], A[k][v]);
    }
  }
  float lt = (ls[0]+ls[1]) + (ls[2]+ls[3]);
  float inv = 1.f/lt;
  size_t baseo=(size_t)n*HC+ch0;
  if constexpr (OUTBF){
    unsigned short* ob = (unsigned short*)out;
    ushort4 o;
    o.x = f2bf(lrelu(((A[0][0]+A[1][0])+(A[2][0]+A[3][0]))*inv+biv[0]));
    o.y = f2bf(lrelu(((A[0][1]+A[1][1])+(A[2][1]+A[3][1]))*inv+biv[1]));
    o.z = f2bf(lrelu(((A[0][2]+A[1][2])+(A[2][2]+A[3][2]))*inv+biv[2]));
    o.w = f2bf(lrelu(((A[0][3]+A[1][3])+(A[2][3]+A[3][3]))*inv+biv[3]));
    *(ushort4*)(ob + baseo) = o;
  } else {
    float* of = (float*)out;
#pragma unroll
    for (int v=0; v<VPT; ++v)
      of[baseo+v] = lrelu(((A[0][v]+A[1][v])+(A[2][v]+A[3][v]))*inv+biv[v]);
  }
}

// ---------------- bf16 MFMA dual GEMM, LDS-staged via global_load_lds (m97 style) -----
template<bool OUTBF>
__global__ __launch_bounds__(256) void gemm_dual_lds(
    const short* __restrict__ Abf,
    const short* __restrict__ WlT, const short* __restrict__ WrT,
    const float* __restrict__ bl, const float* __restrict__ br,
    void* __restrict__ Out, int M, int K, int NcH, int cgrid, int rgrid)
{
  __shared__ short lds[12288];    // A: [0,8192) shorts (128 rows x 64), B: [8192,12288)
  int id = blockIdx.x;
  int xcd = id & 7, slot = id >> 3;
  int nb = slot % cgrid;
  int rowgroup = (slot / cgrid) * 8 + xcd;
  if (rowgroup >= rgrid) return;
  int row0 = rowgroup * 128;
  int NC2 = 2*NcH;
  int halfx = NcH >> 6;
  int isR = nb >= halfx;
  const short* WT = isR ? WrT : WlT;
  const float* bias = isR ? br : bl;
  int col0 = (nb - (isR ? halfx : 0)) * 64;
  int gcol0 = nb * 64;
  int tid = threadIdx.x;
  int lane = tid & 63, wave = tid >> 6;
  int wm = wave >> 1, wn = wave & 1;
  int quad = lane >> 4, l16 = lane & 15;

  const short* asrc[4];
#pragma unroll
  for (int i=0;i<4;++i){
    int c = wave*256 + i*64 + lane;
    int m = c >> 3, j = c & 7;
    int gr = row0 + m; gr = gr < M ? gr : M-1;   // clamp; never stored
    asrc[i] = Abf + (size_t)gr*K + ((j ^ (m & 7)) << 3);
  }
  const short* bsrc[2];
#pragma unroll
  for (int i=0;i<2;++i){
    int c = wave*128 + i*64 + lane;
    int nloc = c >> 3, j = c & 7;
    bsrc[i] = WT + (size_t)(col0 + nloc)*K + ((j ^ (nloc & 7)) << 3);
  }

  float biasv[2] = { bias[col0 + wn*32 + l16], bias[col0 + wn*32 + 16 + l16] };
  f32x4 acc[4][2];
#pragma unroll
  for (int f=0; f<4; ++f)
#pragma unroll
    for (int g=0; g<2; ++g) acc[f][g] = (f32x4){0.f,0.f,0.f,0.f};

  int niter = K >> 6;
  for (int it=0; it<niter; ++it){
    int k0 = it << 6;
#pragma unroll
    for (int i=0;i<4;++i)
      __builtin_amdgcn_global_load_lds(asrc[i] + k0, &lds[(wave*256 + i*64)*8], 16, 0, 0);
#pragma unroll
    for (int i=0;i<2;++i)
      __builtin_amdgcn_global_load_lds(bsrc[i] + k0, &lds[8192 + (wave*128 + i*64)*8], 16, 0, 0);
    __syncthreads();
#pragma unroll
    for (int s=0; s<2; ++s){
      int t = s*4 + quad;
      bf16x8 af[4], bfv[2];
#pragma unroll
      for (int f=0; f<4; ++f){
        int m = wm*64 + f*16 + l16;
        af[f] = *(const bf16x8*)&lds[m*64 + ((t ^ (m & 7)) << 3)];
      }
#pragma unroll
      for (int g=0; g<2; ++g){
        int nloc = wn*32 + g*16 + l16;
        bfv[g] = *(const bf16x8*)&lds[8192 + nloc*64 + ((t ^ (nloc & 7)) << 3)];
      }
#pragma unroll
      for (int f=0; f<4; ++f)
#pragma unroll
        for (int g=0; g<2; ++g)
          acc[f][g] = __builtin_amdgcn_mfma_f32_16x16x32_bf16(af[f], bfv[g], acc[f][g], 0,0,0);
    }
    __syncthreads();
  }

#pragma unroll
  for (int f=0; f<4; ++f){
    int rbase = row0 + wm*64 + f*16 + quad*4;
#pragma unroll
    for (int r=0; r<4; ++r){
      int rr = rbase + r;
      if (rr < M){
#pragma unroll
        for (int g=0; g<2; ++g){
          int cc = gcol0 + wn*32 + g*16 + l16;
          float val = acc[f][g][r] + biasv[g];
          if constexpr (OUTBF) ((unsigned short*)Out)[(size_t)rr*NC2 + cc] = f2bf(val);
          else                 ((float*)Out)[(size_t)rr*NC2 + cc] = val;
        }
      }
    }
  }
}

// ---------------- fused pool (sorted batch, binary search) + MLP head ----------------
__device__ __forceinline__ int lbound(const int* __restrict__ a, int n, int key){
  int lo = 0, hi = n;
  while (lo < hi){ int mid = (lo+hi) >> 1; if (a[mid] < key) lo = mid+1; else hi = mid; }
  return lo;
}

__global__ __launch_bounds__(128) void head_kernel(
    const float* __restrict__ h3, const int* __restrict__ ntype, const int* __restrict__ batch,
    const float* __restrict__ m1w, const float* __restrict__ m1b,
    const float* __restrict__ g1, const float* __restrict__ b1,
    const float* __restrict__ m2w, const float* __restrict__ m2b,
    const float* __restrict__ g2, const float* __restrict__ b2,
    const float* __restrict__ m3w, const float* __restrict__ m3b,
    float* __restrict__ out)
{
  __shared__ float p[128];
  __shared__ float hb[128];
  __shared__ float red[128];
  int b = blockIdx.x, j = threadIdx.x;
  int lo = lbound(batch, NN, b);
  int hi = lbound(batch, NN, b+1);
  float s = 0.f, cnt = 0.f;
  int n = lo;
  for (; n + 3 < hi; n += 4){
    float w0 = (ntype[n]   == 0) ? 1.f : 0.f;
    float w1 = (ntype[n+1] == 0) ? 1.f : 0.f;
    float w2 = (ntype[n+2] == 0) ? 1.f : 0.f;
    float w3 = (ntype[n+3] == 0) ? 1.f : 0.f;
    s += w0*h3[(size_t)n*128 + j]     + w1*h3[(size_t)(n+1)*128 + j]
       + w2*h3[(size_t)(n+2)*128 + j] + w3*h3[(size_t)(n+3)*128 + j];
    cnt += w0 + w1 + w2 + w3;
  }
  for (; n < hi; ++n){
    float w = (ntype[n] == 0) ? 1.f : 0.f;
    s += w*h3[(size_t)n*128 + j];
    cnt += w;
  }
  p[j] = s / fmaxf(cnt, 1.f);
  __syncthreads();
  float a = m1b[j];
  for (int k=0; k<128; ++k) a += p[k]*m1w[k*128 + j];
  red[j] = a; __syncthreads();
  for (int off=64; off>0; off>>=1){ if (j<off) red[j] += red[j+off]; __syncthreads(); }
  float mu = red[0] * (1.f/128.f);
  __syncthreads();
  float d = a - mu;
  red[j] = d*d; __syncthreads();
  for (int off=64; off>0; off>>=1){ if (j<off) red[j] += red[j+off]; __syncthreads(); }
  float var = red[0] * (1.f/128.f);
  __syncthreads();
  hb[j] = lrelu(d * rsqrtf(var + 1e-5f) * g1[j] + b1[j]);
  __syncthreads();
  float a2 = 0.f;
  if (j < 64){
    a2 = m2b[j];
    for (int k=0; k<128; ++k) a2 += hb[k]*m2w[k*64 + j];
  }
  red[j] = (j<64) ? a2 : 0.f; __syncthreads();
  for (int off=64; off>0; off>>=1){ if (j<off) red[j] += red[j+off]; __syncthreads(); }
  float mu2 = red[0] * (1.f/64.f);
  __syncthreads();
  float d2 = a2 - mu2;
  red[j] = (j<64) ? d2*d2 : 0.f; __syncthreads();
  for (int off=64; off>0; off>>=1){ if (j<off) red[j] += red[j+off]; __syncthreads(); }
  float var2 = red[0] * (1.f/64.f);
  __syncthreads();
  if (j < 64) hb[j] = lrelu(d2 * rsqrtf(var2 + 1e-5f) * g2[j] + b2[j]);
  __syncthreads();
  if (j == 0){
    float o = m3b[0];
    for (int k=0; k<64; ++k) o += hb[k]*m3w[k];
    out[b] = o;
  }
}

extern "C" void kernel_launch(void* const* d_in, const int* in_sizes, int n_in,
                              void* d_out, int out_size, void* d_ws, size_t ws_size,
                              hipStream_t stream)
{
  const float* x        = (const float*)d_in[0];
  const int*   ntype    = (const int*)d_in[1];
  const int*   ei       = (const int*)d_in[2];
  const float* eattr    = (const float*)d_in[3];
  const int*   batch    = (const int*)d_in[4];
  const float* vp_w     = (const float*)d_in[5];
  const float* vp_b     = (const float*)d_in[6];
  const float* type_emb = (const float*)d_in[7];
  const float* c1_wl = (const float*)d_in[8];  const float* c1_bl = (const float*)d_in[9];
  const float* c1_wr = (const float*)d_in[10]; const float* c1_br = (const float*)d_in[11];
  const float* c1_we = (const float*)d_in[12]; const float* c1_att= (const float*)d_in[13];
  const float* c1_bias=(const float*)d_in[14];
  const float* c2_wl = (const float*)d_in[15]; const float* c2_bl = (const float*)d_in[16];
  const float* c2_wr = (const float*)d_in[17]; const float* c2_br = (const float*)d_in[18];
  const float* c2_we = (const float*)d_in[19]; const float* c2_att= (const float*)d_in[20];
  const float* c2_bias=(const float*)d_in[21];
  const float* c3_wl = (const float*)d_in[22]; const float* c3_bl = (const float*)d_in[23];
  const float* c3_wr = (const float*)d_in[24]; const float* c3_br = (const float*)d_in[25];
  const float* c3_we = (const float*)d_in[26]; const float* c3_att= (const float*)d_in[27];
  const float* c3_bias=(const float*)d_in[28];
  const float* m1_w = (const float*)d_in[29]; const float* m1_b = (const float*)d_in[30];
  const float* ln1_g= (const float*)d_in[31]; const float* ln1_b= (const float*)d_in[32];
  const float* m2_w = (const float*)d_in[33]; const float* m2_b = (const float*)d_in[34];
  const float* ln2_g= (const float*)d_in[35]; const float* ln2_b= (const float*)d_in[36];
  const float* m3_w = (const float*)d_in[37]; const float* m3_b = (const float*)d_in[38];
  const int* esrc = ei;
  const int* edst = ei + NE;
  float* outp = (float*)d_out;
  (void)in_sizes; (void)n_in; (void)out_size; (void)ws_size;

  // ---- workspace arena ----
  char* w = (char*)d_ws;
  auto alloc = [&](size_t bytes) -> void* {
    void* p = (void*)w;
    w += (bytes + 255) & ~(size_t)255;
    return p;
  };
  unsigned short* h1bf = (unsigned short*)alloc((size_t)NN*1024*2);  // conv1 out, bf16
  unsigned short* X2   = (unsigned short*)alloc((size_t)NN*512*2);   // [xl2 | xr2] bf16
  unsigned short* h2bf = (unsigned short*)alloc((size_t)NN*256*2);   // conv2 out, bf16
  float* X3   = (float*)alloc((size_t)NN*256*4);    // [xl3 | xr3] fp32
  float* h3   = (float*)alloc((size_t)NN*128*4);    // conv3 out (type0 rows only)
  unsigned short* W2lT = (unsigned short*)alloc((size_t)256*1024*2);
  unsigned short* W2rT = (unsigned short*)alloc((size_t)256*1024*2);
  unsigned short* W3lT = (unsigned short*)alloc((size_t)128*256*2);
  unsigned short* W3rT = (unsigned short*)alloc((size_t)128*256*2);
  float* Ul   = (float*)alloc(1024*4);
  float* CTl  = (float*)alloc(2048*4);
  float* Ur   = (float*)alloc(1024*4);
  float* CTr  = (float*)alloc(2048*4);
  const int zero_words = 3*NN;                       // deg, rowctr, loop_sum
  float* zbase = (float*)alloc((size_t)zero_words*4);
  int*   deg      = (int*)zbase;
  int*   rowctr   = (int*)(zbase + NN);
  float* loop_sum = zbase + 2*NN;
  float* loop_attr= (float*)alloc((size_t)NN*4);
  float2* xt      = (float2*)alloc((size_t)NN*8);    // {x, (float)ntype}
  int*   rowptr   = (int*)alloc((size_t)(NN+1)*4);
  int2*  se       = (int2*)alloc((size_t)NE*8);      // {src, ea bits}

  // ---- pipeline (10 dispatches) ----
  prep_kernel<<<180, 256, 0, stream>>>(vp_w, vp_b, type_emb,
      c1_wl, c1_bl, c1_wr, c1_br, Ul, CTl, Ur, CTr,
      c2_wl, c2_wr, c3_wl, c3_wr, W2lT, W2rT, W3lT, W3rT,
      zbase, zero_words);
  count_kernel<<<(NE+255)/256, 256, 0, stream>>>(edst, eattr, deg, loop_sum);
  scan_kernel<<<1, 1024, 0, stream>>>(deg, loop_sum, x, ntype, rowptr, loop_attr, xt);
  fill_kernel<<<(NE+255)/256, 256, 0, stream>>>(esrc, edst, eattr, rowptr, rowctr, se);
  conv1_fused<<<NN/2, 256, 0, stream>>>(rowptr, se, loop_attr, xt,
      Ul, Ur, CTl, CTr, c1_we, c1_att, c1_bias, h1bf);
  // c2: X2[10000,512] bf16, K=1024, NcH=256: cgrid=8, rgrid=79 -> 640 blocks
  gemm_dual_lds<true><<<640, 256, 0, stream>>>(
      (const short*)h1bf, (const short*)W2lT, (const short*)W2rT, c2_bl, c2_br,
      (void*)X2, NN, 1024, 256, 8, 79);
  conv_kernel<2,4,4,false,true,true><<<NN/4, 256, 0, stream>>>(rowptr, se, loop_attr, ntype,
      (const void*)X2, 512, 256, c2_we, c2_att, c2_bias, h2bf);
  // c3: X3[10000,256] fp32, K=256, NcH=128: cgrid=4, rgrid=79 -> 320 blocks
  gemm_dual_lds<false><<<320, 256, 0, stream>>>(
      (const short*)h2bf, (const short*)W3lT, (const short*)W3rT, c3_bl, c3_br,
      (void*)X3, NN, 256, 128, 4, 79);
  conv_kernel<1,4,2,true,false,false><<<NN/4, 256, 0, stream>>>(rowptr, se, loop_attr, ntype,
      (const void*)X3, 256, 128, c3_we, c3_att, c3_bias, h3);
  head_kernel<<<NBATCH, 128, 0, stream>>>(h3, ntype, batch, m1_w, m1_b, ln1_g, ln1_b,
                                          m2_w, m2_b, ln2_g, ln2_b, m3_w, m3_b, outp);
}